// Round 1
// baseline (1282.198 us; speedup 1.0000x reference)
//
#include <hip/hip_runtime.h>
#include <stdint.h>

// VoxelLayer: reproduce JAX voxel-grid downsample ×2 with bit-exact
// Threefry-2x32 (partitionable mode) index sampling.
//
// Layer 1: x (16,3,262144) f32, vox=0.05 -> out1 (16,3,131072)
// Layer 2: out1, vox=0.1 -> out2 (16,3,65536)
// d_out = [out1 | out2] flat.

struct KeyArr {
  uint32_t k0[16];
  uint32_t k1[16];
};

__host__ __device__ inline void tf2x32(uint32_t k0, uint32_t k1,
                                       uint32_t c0, uint32_t c1,
                                       uint32_t& o0, uint32_t& o1) {
  const uint32_t ks0 = k0, ks1 = k1, ks2 = k0 ^ k1 ^ 0x1BD11BDAu;
  uint32_t x0 = c0 + ks0, x1 = c1 + ks1;
#define TF_R(r) { x0 += x1; x1 = (x1 << (r)) | (x1 >> (32 - (r))); x1 ^= x0; }
  TF_R(13) TF_R(15) TF_R(26) TF_R(6)
  x0 += ks1; x1 += ks2 + 1u;
  TF_R(17) TF_R(29) TF_R(16) TF_R(24)
  x0 += ks2; x1 += ks0 + 2u;
  TF_R(13) TF_R(15) TF_R(26) TF_R(6)
  x0 += ks0; x1 += ks1 + 3u;
  TF_R(17) TF_R(29) TF_R(16) TF_R(24)
  x0 += ks1; x1 += ks2 + 4u;
  TF_R(13) TF_R(15) TF_R(26) TF_R(6)
  x0 += ks2; x1 += ks0 + 5u;
#undef TF_R
  o0 = x0; o1 = x1;
}

// ---- init workspace (cnt/sums zero, min to +inf bits, numvox zero) ----
__global__ void init_ws_kernel(unsigned int* cnt, unsigned long long* sums,
                               int cells, unsigned int* mnbits,
                               unsigned int* numvox) {
  int i = blockIdx.x * blockDim.x + threadIdx.x;
  for (int j = i; j < cells; j += gridDim.x * blockDim.x) {
    cnt[j] = 0u;
    sums[3 * (size_t)j + 0] = 0ull;
    sums[3 * (size_t)j + 1] = 0ull;
    sums[3 * (size_t)j + 2] = 0ull;
  }
  if (i < 48) mnbits[i] = 0x7F800000u;  // +inf
  if (i < 16) numvox[i] = 0u;
}

// ---- per-(batch,coord) min over N points ----
__global__ void min_kernel(const float* __restrict__ in, int N,
                           unsigned int* mnbits) {
  int row = blockIdx.y;  // b*3+c in [0,48)
  const float4* p = (const float4*)(in + (size_t)row * N);
  int n4 = N >> 2;
  float m = __int_as_float(0x7F800000);
  for (int i = blockIdx.x * blockDim.x + threadIdx.x; i < n4;
       i += gridDim.x * blockDim.x) {
    float4 v = p[i];
    m = fminf(m, fminf(fminf(v.x, v.y), fminf(v.z, v.w)));
  }
  for (int off = 32; off > 0; off >>= 1)
    m = fminf(m, __shfl_down(m, off, 64));
  if ((threadIdx.x & 63) == 0)
    atomicMin((int*)&mnbits[row], __float_as_int(m));  // all values >= 0
}

// ---- accumulate per-voxel count + fixed-point coordinate sums ----
__global__ void accum_kernel(const float* __restrict__ in, int N, int G, int S,
                             float vox, const unsigned int* __restrict__ mnbits,
                             unsigned int* cnt, unsigned long long* sums) {
  int n = blockIdx.x * blockDim.x + threadIdx.x;
  int b = blockIdx.y;
  if (n >= N) return;
  const float* base = in + (size_t)b * 3 * N;
  float p0 = base[n];
  float p1 = base[(size_t)N + n];
  float p2 = base[2 * (size_t)N + n];
  float m0 = __uint_as_float(mnbits[b * 3 + 0]);
  float m1 = __uint_as_float(mnbits[b * 3 + 1]);
  float m2 = __uint_as_float(mnbits[b * 3 + 2]);
  // exact IEEE: sub, div, floor — identical to XLA
  int v0 = (int)floorf((p0 - m0) / vox);
  int v1 = (int)floorf((p1 - m1) / vox);
  int v2 = (int)floorf((p2 - m2) / vox);
  int lin = (v0 * S + v1) * S + v2;  // S >= dims, preserves lex order
  size_t cell = (size_t)b * G + lin;
  atomicAdd(&cnt[cell], 1u);
  // Q32.32 fixed point (values in [0,1)) -> deterministic sums
  unsigned long long f0 = (unsigned long long)((double)p0 * 4294967296.0);
  unsigned long long f1 = (unsigned long long)((double)p1 * 4294967296.0);
  unsigned long long f2 = (unsigned long long)((double)p2 * 4294967296.0);
  atomicAdd(&sums[cell * 3 + 0], f0);
  atomicAdd(&sums[cell * 3 + 1], f1);
  atomicAdd(&sums[cell * 3 + 2], f2);
}

// ---- compact occupied voxels in ascending-lin order, write means ----
__global__ void compact_kernel(int G, const unsigned int* __restrict__ cnt,
                               const unsigned long long* __restrict__ sums,
                               float* __restrict__ means,
                               unsigned int* __restrict__ numvox) {
  int b = blockIdx.x;
  int tid = threadIdx.x;  // 256 threads
  __shared__ unsigned int s_scan[256];
  __shared__ unsigned int s_base;
  if (tid == 0) s_base = 0u;
  __syncthreads();
  for (int t0 = 0; t0 < G; t0 += 256) {
    int cell = t0 + tid;
    unsigned int cv = (cell < G) ? cnt[(size_t)b * G + cell] : 0u;
    unsigned int occ = (cv > 0u) ? 1u : 0u;
    s_scan[tid] = occ;
    __syncthreads();
    for (int off = 1; off < 256; off <<= 1) {
      unsigned int v = (tid >= off) ? s_scan[tid - off] : 0u;
      __syncthreads();
      s_scan[tid] += v;
      __syncthreads();
    }
    if (occ) {
      unsigned int seg = s_base + s_scan[tid] - 1u;
      size_t ci = (size_t)b * G + cell;
      double inv = 1.0 / (4294967296.0 * (double)cv);
      float* mo = means + ((size_t)b * G + seg) * 3;
      mo[0] = (float)((double)sums[ci * 3 + 0] * inv);
      mo[1] = (float)((double)sums[ci * 3 + 1] * inv);
      mo[2] = (float)((double)sums[ci * 3 + 2] * inv);
    }
    __syncthreads();
    if (tid == 0) s_base += s_scan[255];
    __syncthreads();
  }
  if (tid == 0) numvox[b] = s_base;
}

// ---- sample L voxel centroids via JAX threefry uniforms ----
__global__ void sample_kernel(int L, int G, const float* __restrict__ means,
                              const unsigned int* __restrict__ numvox,
                              KeyArr keys, float* __restrict__ out) {
  int l = blockIdx.x * blockDim.x + threadIdx.x;
  int b = blockIdx.y;
  if (l >= L) return;
  uint32_t w0, w1;
  tf2x32(keys.k0[b], keys.k1[b], 0u, (uint32_t)l, w0, w1);
  uint32_t bits = w0 ^ w1;  // partitionable 32-bit fold
  float u = __uint_as_float((bits >> 9) | 0x3F800000u) - 1.0f;
  unsigned int nv = numvox[b];
  int idx = (int)(u * (float)nv);  // f32 mul RN, trunc toward zero
  int nvm1 = (int)nv - 1;
  if (idx > nvm1) idx = nvm1;
  const float* mo = means + ((size_t)b * G + idx) * 3;
  out[((size_t)b * 3 + 0) * L + l] = mo[0];
  out[((size_t)b * 3 + 1) * L + l] = mo[1];
  out[((size_t)b * 3 + 2) * L + l] = mo[2];
}

static void run_layer(const float* in, int N, int L, float vox, int S, int G,
                      const KeyArr& keys, float* out, unsigned int* cnt,
                      unsigned long long* sums, float* means,
                      unsigned int* mnbits, unsigned int* numvox,
                      hipStream_t stream) {
  int cells = 16 * G;
  init_ws_kernel<<<dim3((cells + 255) / 256), dim3(256), 0, stream>>>(
      cnt, sums, cells, mnbits, numvox);
  min_kernel<<<dim3(32, 48), dim3(256), 0, stream>>>(in, N, mnbits);
  accum_kernel<<<dim3(N / 256, 16), dim3(256), 0, stream>>>(
      in, N, G, S, vox, mnbits, cnt, sums);
  compact_kernel<<<dim3(16), dim3(256), 0, stream>>>(G, cnt, sums, means,
                                                     numvox);
  sample_kernel<<<dim3((L + 255) / 256, 16), dim3(256), 0, stream>>>(
      L, G, means, numvox, keys, out);
}

extern "C" void kernel_launch(void* const* d_in, const int* in_sizes, int n_in,
                              void* d_out, int out_size, void* d_ws,
                              size_t ws_size, hipStream_t stream) {
  const float* x = (const float*)d_in[0];
  float* out = (float*)d_out;

  // ---- JAX key derivation on host (threefry partitionable split) ----
  // root = key(42) = (0, 42); k1 = tf(root,(0,0)); k2 = tf(root,(0,1))
  // keys_b = tf(k, (0, b)) for b in 0..15
  uint32_t k1a, k1b, k2a, k2b;
  tf2x32(0u, 42u, 0u, 0u, k1a, k1b);
  tf2x32(0u, 42u, 0u, 1u, k2a, k2b);
  KeyArr keys1, keys2;
  for (int b = 0; b < 16; ++b) {
    tf2x32(k1a, k1b, 0u, (uint32_t)b, keys1.k0[b], keys1.k1[b]);
    tf2x32(k2a, k2b, 0u, (uint32_t)b, keys2.k0[b], keys2.k1[b]);
  }

  // ---- workspace layout (needs ~5.2 MB) ----
  uint8_t* w = (uint8_t*)d_ws;
  unsigned int* cnt = (unsigned int*)w;                       // 16*8000*4   = 512000
  unsigned long long* sums = (unsigned long long*)(w + 512000);  // *3*8    = 3072000
  float* means = (float*)(w + 512000 + 3072000);              // 16*8000*3*4 = 1536000
  unsigned int* mnbits = (unsigned int*)(w + 5120000);        // 48*4
  unsigned int* numvox = (unsigned int*)(w + 5120000 + 192);  // 16*4

  const int N1 = 262144, L1 = 131072, L2 = 65536;
  float* out1 = out;                       // (16,3,131072)
  float* out2 = out + (size_t)16 * 3 * L1; // (16,3,65536)

  // Layer 1: vox=0.05, stride 20 (v<=19 proven), grid 8000 cells
  run_layer(x, N1, L1, 0.05f, 20, 8000, keys1, out1, cnt, sums, means, mnbits,
            numvox, stream);
  // Layer 2: input = out1, vox=0.1, stride 10 (v<=9 proven), grid 1000 cells
  run_layer(out1, L1, L2, 0.1f, 10, 1000, keys2, out2, cnt, sums, means,
            mnbits, numvox, stream);
}

// Round 2
// 217.562 us; speedup vs baseline: 5.8935x; 5.8935x over previous
//
#include <hip/hip_runtime.h>
#include <stdint.h>

// VoxelLayer: JAX voxel-grid downsample ×2, bit-exact Threefry-2x32
// (partitionable) index sampling. Round 2: LDS-privatized accumulation.
//
// Per-cell packed state (deterministic integer fixed-point, Q20):
//   A = (ysum << 32) | xsum
//   B = (cnt  << 32) | zsum
// Safe while per-voxel count < 4096 (observed max ~70 / ~190).

struct KeyArr {
  uint32_t k0[16];
  uint32_t k1[16];
};

__host__ __device__ inline void tf2x32(uint32_t k0, uint32_t k1,
                                       uint32_t c0, uint32_t c1,
                                       uint32_t& o0, uint32_t& o1) {
  const uint32_t ks0 = k0, ks1 = k1, ks2 = k0 ^ k1 ^ 0x1BD11BDAu;
  uint32_t x0 = c0 + ks0, x1 = c1 + ks1;
#define TF_R(r) { x0 += x1; x1 = (x1 << (r)) | (x1 >> (32 - (r))); x1 ^= x0; }
  TF_R(13) TF_R(15) TF_R(26) TF_R(6)
  x0 += ks1; x1 += ks2 + 1u;
  TF_R(17) TF_R(29) TF_R(16) TF_R(24)
  x0 += ks2; x1 += ks0 + 2u;
  TF_R(13) TF_R(15) TF_R(26) TF_R(6)
  x0 += ks0; x1 += ks1 + 3u;
  TF_R(17) TF_R(29) TF_R(16) TF_R(24)
  x0 += ks1; x1 += ks2 + 4u;
  TF_R(13) TF_R(15) TF_R(26) TF_R(6)
  x0 += ks2; x1 += ks0 + 5u;
#undef TF_R
  o0 = x0; o1 = x1;
}

// ---- init workspace: zero packed cells, min to +inf, numvox ----
__global__ void init_ws_kernel(unsigned long long* cells, int ncells2,
                               unsigned int* mnbits, unsigned int* numvox) {
  int i = blockIdx.x * blockDim.x + threadIdx.x;
  for (int j = i; j < ncells2; j += gridDim.x * blockDim.x) cells[j] = 0ull;
  if (i < 48) mnbits[i] = 0x7F800000u;  // +inf
  if (i < 16) numvox[i] = 0u;
}

// ---- per-(batch,coord) min over N points ----
__global__ void min_kernel(const float* __restrict__ in, int N,
                           unsigned int* mnbits) {
  int row = blockIdx.y;  // b*3+c in [0,48)
  const float4* p = (const float4*)(in + (size_t)row * N);
  int n4 = N >> 2;
  float m = __int_as_float(0x7F800000);
  for (int i = blockIdx.x * blockDim.x + threadIdx.x; i < n4;
       i += gridDim.x * blockDim.x) {
    float4 v = p[i];
    m = fminf(m, fminf(fminf(v.x, v.y), fminf(v.z, v.w)));
  }
  for (int off = 32; off > 0; off >>= 1)
    m = fminf(m, __shfl_down(m, off, 64));
  if ((threadIdx.x & 63) == 0)
    atomicMin((int*)&mnbits[row], __float_as_int(m));  // all values >= 0
}

// ---- LDS-privatized accumulation, then sparse global merge ----
template <int G, int S>
__global__ __launch_bounds__(1024) void accum_lds_kernel(
    const float* __restrict__ in, int N, int pts_per_block, float vox,
    const unsigned int* __restrict__ mnbits,
    unsigned long long* __restrict__ cells /* [16][G][2] */) {
  extern __shared__ unsigned long long lds[];  // [G][2]
  int b = blockIdx.y;
  for (int i = threadIdx.x; i < 2 * G; i += blockDim.x) lds[i] = 0ull;
  __syncthreads();

  const float* base = in + (size_t)b * 3 * N;
  float m0 = __uint_as_float(mnbits[b * 3 + 0]);
  float m1 = __uint_as_float(mnbits[b * 3 + 1]);
  float m2 = __uint_as_float(mnbits[b * 3 + 2]);
  int start = blockIdx.x * pts_per_block;
  for (int i = threadIdx.x; i < pts_per_block; i += blockDim.x) {
    int n = start + i;
    float p0 = base[n];
    float p1 = base[(size_t)N + n];
    float p2 = base[2 * (size_t)N + n];
    // exact IEEE sub/div/floor — identical to XLA
    int v0 = (int)floorf((p0 - m0) / vox);
    int v1 = (int)floorf((p1 - m1) / vox);
    int v2 = (int)floorf((p2 - m2) / vox);
    int lin = (v0 * S + v1) * S + v2;  // S >= dims: lex order preserved
    // Q20 fixed point (p in [0,1): p*2^20 exact in f32, trunc = floor)
    unsigned int qx = (unsigned int)(p0 * 1048576.0f);
    unsigned int qy = (unsigned int)(p1 * 1048576.0f);
    unsigned int qz = (unsigned int)(p2 * 1048576.0f);
    atomicAdd(&lds[2 * lin],
              ((unsigned long long)qy << 32) | (unsigned long long)qx);
    atomicAdd(&lds[2 * lin + 1],
              (1ull << 32) | (unsigned long long)qz);
  }
  __syncthreads();

  unsigned long long* gc = cells + (size_t)b * G * 2;
  for (int c = threadIdx.x; c < G; c += blockDim.x) {
    unsigned long long Bv = lds[2 * c + 1];
    if (Bv) {
      atomicAdd(&gc[2 * c], lds[2 * c]);
      atomicAdd(&gc[2 * c + 1], Bv);
    }
  }
}

// ---- compact occupied voxels (ascending lin), write means ----
__global__ void compact_kernel(int G,
                               const unsigned long long* __restrict__ cells,
                               float* __restrict__ means,
                               unsigned int* __restrict__ numvox) {
  int b = blockIdx.x;
  int tid = threadIdx.x;  // 256 threads
  __shared__ unsigned int s_scan[256];
  __shared__ unsigned int s_base;
  if (tid == 0) s_base = 0u;
  __syncthreads();
  for (int t0 = 0; t0 < G; t0 += 256) {
    int cell = t0 + tid;
    unsigned long long Av = 0ull, Bv = 0ull;
    if (cell < G) {
      size_t ci = ((size_t)b * G + cell) * 2;
      Av = cells[ci];
      Bv = cells[ci + 1];
    }
    unsigned int cv = (unsigned int)(Bv >> 32);
    unsigned int occ = (cv > 0u) ? 1u : 0u;
    s_scan[tid] = occ;
    __syncthreads();
    for (int off = 1; off < 256; off <<= 1) {
      unsigned int v = (tid >= off) ? s_scan[tid - off] : 0u;
      __syncthreads();
      s_scan[tid] += v;
      __syncthreads();
    }
    if (occ) {
      unsigned int seg = s_base + s_scan[tid] - 1u;
      double inv = 1.0 / (1048576.0 * (double)cv);
      float* mo = means + ((size_t)b * G + seg) * 3;
      mo[0] = (float)((double)(unsigned int)Av * inv);
      mo[1] = (float)((double)(unsigned int)(Av >> 32) * inv);
      mo[2] = (float)((double)(unsigned int)Bv * inv);
    }
    __syncthreads();
    if (tid == 0) s_base += s_scan[255];
    __syncthreads();
  }
  if (tid == 0) numvox[b] = s_base;
}

// ---- sample L voxel centroids via JAX threefry uniforms ----
__global__ void sample_kernel(int L, int G, const float* __restrict__ means,
                              const unsigned int* __restrict__ numvox,
                              KeyArr keys, float* __restrict__ out) {
  int l = blockIdx.x * blockDim.x + threadIdx.x;
  int b = blockIdx.y;
  if (l >= L) return;
  uint32_t w0, w1;
  tf2x32(keys.k0[b], keys.k1[b], 0u, (uint32_t)l, w0, w1);
  uint32_t bits = w0 ^ w1;  // partitionable 32-bit fold
  float u = __uint_as_float((bits >> 9) | 0x3F800000u) - 1.0f;
  unsigned int nv = numvox[b];
  int idx = (int)(u * (float)nv);  // f32 mul RN, trunc toward zero
  int nvm1 = (int)nv - 1;
  if (idx > nvm1) idx = nvm1;
  const float* mo = means + ((size_t)b * G + idx) * 3;
  out[((size_t)b * 3 + 0) * L + l] = mo[0];
  out[((size_t)b * 3 + 1) * L + l] = mo[1];
  out[((size_t)b * 3 + 2) * L + l] = mo[2];
}

template <int G, int S>
static void run_layer(const float* in, int N, int L, int chunks, float vox,
                      const KeyArr& keys, float* out,
                      unsigned long long* cells, float* means,
                      unsigned int* mnbits, unsigned int* numvox,
                      hipStream_t stream) {
  init_ws_kernel<<<dim3(64), dim3(256), 0, stream>>>(cells, 16 * G * 2,
                                                     mnbits, numvox);
  min_kernel<<<dim3(32, 48), dim3(256), 0, stream>>>(in, N, mnbits);
  accum_lds_kernel<G, S>
      <<<dim3(chunks, 16), dim3(1024), (size_t)G * 16, stream>>>(
          in, N, N / chunks, vox, mnbits, cells);
  compact_kernel<<<dim3(16), dim3(256), 0, stream>>>(G, cells, means, numvox);
  sample_kernel<<<dim3((L + 255) / 256, 16), dim3(256), 0, stream>>>(
      L, G, means, numvox, keys, out);
}

extern "C" void kernel_launch(void* const* d_in, const int* in_sizes, int n_in,
                              void* d_out, int out_size, void* d_ws,
                              size_t ws_size, hipStream_t stream) {
  const float* x = (const float*)d_in[0];
  float* out = (float*)d_out;

  // ---- JAX key derivation (threefry partitionable split) ----
  uint32_t k1a, k1b, k2a, k2b;
  tf2x32(0u, 42u, 0u, 0u, k1a, k1b);
  tf2x32(0u, 42u, 0u, 1u, k2a, k2b);
  KeyArr keys1, keys2;
  for (int b = 0; b < 16; ++b) {
    tf2x32(k1a, k1b, 0u, (uint32_t)b, keys1.k0[b], keys1.k1[b]);
    tf2x32(k2a, k2b, 0u, (uint32_t)b, keys2.k0[b], keys2.k1[b]);
  }

  // ---- workspace layout (~3.6 MB) ----
  uint8_t* w = (uint8_t*)d_ws;
  unsigned long long* cells = (unsigned long long*)w;   // 16*8000*2*8 = 2048000
  float* means = (float*)(w + 2048000);                 // 16*8000*3*4 = 1536000
  unsigned int* mnbits = (unsigned int*)(w + 2048000 + 1536000);  // 48*4
  unsigned int* numvox = (unsigned int*)(w + 2048000 + 1536000 + 192);

  const int N1 = 262144, L1 = 131072, L2 = 65536;
  float* out1 = out;                        // (16,3,131072)
  float* out2 = out + (size_t)16 * 3 * L1;  // (16,3,65536)

  // Layer 1: vox=0.05, stride 20 (v<=19), G=8000, LDS 128000 B, 8 chunks
  run_layer<8000, 20>(x, N1, L1, 8, 0.05f, keys1, out1, cells, means, mnbits,
                      numvox, stream);
  // Layer 2: vox=0.1, stride 10 (v<=9), G=1000, LDS 16000 B, 8 chunks
  run_layer<1000, 10>(out1, L1, L2, 8, 0.1f, keys2, out2, cells, means, mnbits,
                      numvox, stream);
}